// Round 9
// baseline (247.782 us; speedup 1.0000x reference)
//
#include <hip/hip_runtime.h>

typedef unsigned short u16;
typedef unsigned int u32;
typedef __bf16 bf16_t;
typedef bf16_t bf16x8 __attribute__((ext_vector_type(8)));
typedef float f32x4 __attribute__((ext_vector_type(4)));
typedef u32 u32x4 __attribute__((ext_vector_type(4)));

#define BATCH 8
#define CH 128
#define NSP 4096  // 64*64 spatial
#define LOG2E 1.44269504088896f

static __device__ __forceinline__ u16 f2bf(float f) {
  u32 u = __builtin_bit_cast(u32, f);
  u32 r = u + 0x7FFFu + ((u >> 16) & 1u);  // RNE
  return (u16)(r >> 16);
}

static __device__ __forceinline__ bf16x8 ld_bf8(const u16* p) {
  return __builtin_bit_cast(bf16x8, *(const u32x4*)p);
}

static __device__ __forceinline__ f32x4 mfma16(bf16x8 a, bf16x8 b, f32x4 c) {
  return __builtin_amdgcn_mfma_f32_16x16x32_bf16(a, b, c, 0, 0, 0);
}

static __device__ __forceinline__ u32 cvt_pk(float lo, float hi) {
  u32 r;
  asm("v_cvt_pk_bf16_f32 %0, %1, %2" : "=v"(r) : "v"(lo), "v"(hi));
  return r;
}

static __device__ __forceinline__ float fast_exp2(float x) {
#if __has_builtin(__builtin_amdgcn_exp2f)
  return __builtin_amdgcn_exp2f(x);
#else
  return exp2f(x);
#endif
}

static __device__ __forceinline__ void gl2lds16(const u16* g, u16* l) {
  __builtin_amdgcn_global_load_lds((const __attribute__((address_space(1))) void*)g,
                                   (__attribute__((address_space(3))) void*)l, 16, 0, 0);
}

// ---------------- GroupNorm stats (+ fused weight fp32->bf16 convert) ----------------
__global__ __launch_bounds__(256) void gn_stats_kernel(const float* __restrict__ x,
                                                       float* __restrict__ stats,
                                                       const float* __restrict__ wq,
                                                       const float* __restrict__ wk,
                                                       const float* __restrict__ wv,
                                                       const float* __restrict__ wo,
                                                       u16* __restrict__ wbf) {
  int bg = blockIdx.x;  // 0..255
  {
    int widx = bg * 256 + threadIdx.x;
    int m = widx >> 14, r = widx & 16383;
    const float* s = (m == 0) ? wq : (m == 1) ? wk : (m == 2) ? wv : wo;
    wbf[widx] = f2bf(s[r]);
  }
  const float4* p = (const float4*)(x + (size_t)bg * 16384);
  float s = 0.f, ss = 0.f;
  for (int i = threadIdx.x; i < 4096; i += 256) {
    float4 v = p[i];
    s += v.x + v.y + v.z + v.w;
    ss += v.x * v.x + v.y * v.y + v.z * v.z + v.w * v.w;
  }
  for (int off = 32; off; off >>= 1) {
    s += __shfl_xor(s, off);
    ss += __shfl_xor(ss, off);
  }
  __shared__ float rs[4], rss[4];
  int wave = threadIdx.x >> 6;
  if ((threadIdx.x & 63) == 0) { rs[wave] = s; rss[wave] = ss; }
  __syncthreads();
  if (threadIdx.x == 0) {
    s = rs[0] + rs[1] + rs[2] + rs[3];
    ss = rss[0] + rss[1] + rss[2] + rss[3];
    float mean = s * (1.f / 16384.f);
    float var = ss * (1.f / 16384.f) - mean * mean;
    stats[2 * bg] = mean;
    stats[2 * bg + 1] = rsqrtf(var + 1e-5f);
  }
}

// ---------------- GN apply + transpose (b,c,n) -> xd (b,n,c) bf16 ----------------
__global__ __launch_bounds__(256) void gn_apply_kernel(const float* __restrict__ x,
                                                       const float* __restrict__ stats,
                                                       const float* __restrict__ gnw,
                                                       const float* __restrict__ gnb,
                                                       u16* __restrict__ xd) {
  __shared__ float tile[32][129];
  __shared__ float sc[128], sh[128];
  int b = blockIdx.y, n0 = blockIdx.x * 32;
  int t = threadIdx.x;
  if (t < 128) {
    float mean = stats[2 * (b * 32 + (t >> 2))];
    float rstd = stats[2 * (b * 32 + (t >> 2)) + 1];
    float w = gnw[t];
    sc[t] = rstd * w;
    sh[t] = gnb[t] - mean * rstd * w;
  }
  const float* xb = x + (size_t)b * (CH * NSP);
#pragma unroll
  for (int r = 0; r < 16; ++r) {
    int e = t + r * 256;
    int c = e >> 5, j = e & 31;
    tile[j][c] = xb[(size_t)c * NSP + n0 + j];
  }
  __syncthreads();
  u16* xdb = xd + ((size_t)b * NSP + n0) * CH;
#pragma unroll
  for (int r = 0; r < 16; ++r) {
    int e = t + r * 256;
    int j = e >> 7, c = e & 127;
    xdb[(size_t)j * CH + c] = f2bf(tile[j][c] * sc[c] + sh[c]);
  }
}

// ---------------- fused QKV projections ----------------
// q: (b,n,c) bf16, pre-scaled by log2(e)/sqrt(C).
// k: (b,n,c') bf16 with SLOT PERMUTATION c' = ((c>>3) ^ (n&7))*8 + (c&7):
//    linear gl2lds staging then reading fragment (kk,lg) at slot (kk*4+lg)^(n&7)
//    is both correct and LDS-bank-conflict-free.
// v: (b,c,j') bf16 in PV-FRAGMENT order: within each 64-key tile, fragment
//    fr = kk2*4+lg (elements e -> keys kk2*32 + lg*4 + (e<4 ? e : 12+e)) is
//    stored at slot s = fr ^ (c&7). Inverse for key jj:
//    kk2 = jj>>5, lg = (jj&15)>>2, e = (jj&3) + (jj&16 ? 4 : 0).
__global__ __launch_bounds__(256) void qkv_kernel(const u16* __restrict__ xd,
                                                  const u16* __restrict__ wqb,
                                                  const u16* __restrict__ wkb,
                                                  const u16* __restrict__ wvb,
                                                  const float* __restrict__ bq,
                                                  const float* __restrict__ bk,
                                                  const float* __restrict__ bv,
                                                  u16* __restrict__ q, u16* __restrict__ k,
                                                  u16* __restrict__ v) {
  int b = blockIdx.y;
  int wave = threadIdx.x >> 6, lane = threadIdx.x & 63;
  int lr = lane & 15, lg = lane >> 4;
  int n_base = blockIdx.x * 64 + wave * 16;
  const u16* xrow = xd + ((size_t)b * NSP + n_base + lr) * CH;
  f32x4 accq[8] = {}, acck[8] = {}, accv[8] = {};
#pragma unroll
  for (int kk = 0; kk < 4; ++kk) {
    int coff = kk * 32 + lg * 8;
    bf16x8 xa = ld_bf8(xrow + coff);
#pragma unroll
    for (int ot = 0; ot < 8; ++ot) {
      int woff = (ot * 16 + lr) * CH + coff;
      bf16x8 wqf = ld_bf8(wqb + woff);
      bf16x8 wkf = ld_bf8(wkb + woff);
      bf16x8 wvf = ld_bf8(wvb + woff);
      accq[ot] = mfma16(xa, wqf, accq[ot]);
      acck[ot] = mfma16(xa, wkf, acck[ot]);
      accv[ot] = mfma16(wvf, xa, accv[ot]);
    }
  }
  const float qscale = 0.08838834764831845f * LOG2E;  // log2e/sqrt(128)
  // v-store fragment coords for this lane: key jj = wave*16 + lr within the tile
  int jj = wave * 16 + lr;
  int frv = (jj >> 5) * 4 + ((jj & 15) >> 2);  // kk2*4 + lg_v
  int ev = (lr & 3) + ((wave & 1) << 2);       // element within fragment
#pragma unroll
  for (int ot = 0; ot < 8; ++ot) {
    int o_col = ot * 16 + lr;
    float bqv = bq[o_col], bkv = bk[o_col];
#pragma unroll
    for (int r = 0; r < 4; ++r) {
      int nrow = n_base + lg * 4 + r;
      q[((size_t)b * NSP + nrow) * CH + o_col] = f2bf((accq[ot][r] + bqv) * qscale);
      int cperm = ((((o_col >> 3) ^ (nrow & 7)) << 3)) | (o_col & 7);
      k[((size_t)b * NSP + nrow) * CH + cperm] = f2bf(acck[ot][r] + bkv);
    }
#pragma unroll
    for (int r = 0; r < 4; ++r) {
      int c = ot * 16 + lg * 4 + r;  // v output channel
      int slot = frv ^ (c & 7);
      v[((size_t)(b * CH + c)) * NSP + blockIdx.x * 64 + slot * 8 + ev] =
          f2bf(accv[ot][r] + bv[c]);
    }
  }
}

// ---------------- flash attention (no-max, qt=4: 64 q-rows/wave, KV-split=4) --------
// 4 waves x 64 q-rows = 256 q-rows/block; KV tile 64; 16 iters/block; grid 512
// (b = id&7 -> XCD-local K/V; 2 blocks/CU). K,V double-buffered via LINEAR
// global_load_lds (global layouts pre-permuted so ds_reads are conflict-free).
// One barrier/iter; t+1 stages issue right after the barrier, waited a full
// iteration later by vmcnt(0).
// REGISTER DIET vs round 8 (which spilled: 205MB cold writes): softmax phased
// per 16-key group j -> s[4] (16 regs) instead of s[4][2] (32); exp2 feeds
// cvt_pk directly; paw[4] built incrementally. Peak live ~= oacc 128 (AGPR) +
// qa 64 + s 16 + paw 16 + transients < 256 unified.
__global__ __launch_bounds__(256, 2) void attn_kernel(const u16* __restrict__ q,
                                                      const u16* __restrict__ k,
                                                      const u16* __restrict__ v,
                                                      u16* __restrict__ part0,
                                                      u16* __restrict__ part1,
                                                      u16* __restrict__ part2,
                                                      u16* __restrict__ part3,
                                                      float* __restrict__ lbuf) {
  __shared__ __align__(16) u16 kbuf[2][64 * 128];
  __shared__ __align__(16) u16 vbuf[2][128 * 64];
  int id = blockIdx.x;
  int b = id & 7;
  int qblk = (id >> 3) & 15;
  int split = id >> 7;  // 0..3
  int wave = threadIdx.x >> 6, lane = threadIdx.x & 63;
  int lr = lane & 15, lg = lane >> 4;
  int i_base = qblk * 256 + wave * 64;
  int t0 = split * 16, t1 = t0 + 16;

  const u16* kg = k + (size_t)b * NSP * CH;
  const u16* vg = v + (size_t)b * CH * NSP;

  // staging (linear): K = 4 x 1024B (4 rows of 256B each); V = 4 x 1024B (8 rows of 128B)
  auto STAGEK = [&](int t, int bi) {
    const u16* src = kg + ((size_t)(t * 64 + wave * 16)) * CH + lane * 8;
    u16* dst = &kbuf[bi][wave * 16 * 128];
#pragma unroll
    for (int g = 0; g < 4; ++g) gl2lds16(src + g * 512, dst + g * 512);
  };
  int vco = wave * 32 + (lane >> 3);
  auto STAGEV = [&](int t, int bi) {
    const u16* src = vg + t * 64 + (lane & 7) * 8;
    u16* dst = &vbuf[bi][wave * 32 * 64];
#pragma unroll
    for (int g = 0; g < 4; ++g) gl2lds16(src + (size_t)(vco + g * 8) * NSP, dst + g * 512);
  };

  STAGEK(t0, 0);
  STAGEV(t0, 0);

  // Q fragments resident: 4 q-tiles x 4 c-chunks (B-operand: q-row at lane&15)
  bf16x8 qa[4][4];
#pragma unroll
  for (int qt = 0; qt < 4; ++qt) {
    const u16* qrow = q + ((size_t)b * NSP + i_base + qt * 16 + lr) * CH;
#pragma unroll
    for (int kk = 0; kk < 4; ++kk) qa[qt][kk] = ld_bf8(qrow + kk * 32 + lg * 8);
  }

  f32x4 oacc[4][8] = {};
  float lsum[4] = {0.f, 0.f, 0.f, 0.f};

  for (int t = t0; t < t1; ++t) {
    int bi = t & 1;
    const u16* kb = kbuf[bi];
    const u16* vb = vbuf[bi];
    asm volatile("s_waitcnt vmcnt(0)" ::: "memory");  // stages for t (issued iter t-1)
    __builtin_amdgcn_s_barrier();
    __builtin_amdgcn_sched_barrier(0);
    if (t + 1 < t1) {  // prefetch t+1 into the opposite buffers (full iter to land)
      STAGEK(t + 1, bi ^ 1);
      STAGEV(t + 1, bi ^ 1);
    }
    __builtin_amdgcn_sched_barrier(0);

    // two phases: ph=0 -> keys 0..31; ph=1 -> keys 32..63
#pragma unroll
    for (int ph = 0; ph < 2; ++ph) {
      u32x4 paw[4];
      // two 16-key sub-steps: j=0 -> paw[.][0..1], j=1 -> paw[.][2..3]
#pragma unroll
      for (int j = 0; j < 2; ++j) {
        f32x4 s[4] = {};
        int row = (ph * 2 + j) * 16 + lr;
        __builtin_amdgcn_s_setprio(1);
#pragma unroll
        for (int kk = 0; kk < 4; ++kk) {
          bf16x8 kf = ld_bf8(kb + row * 128 + (((kk * 4 + lg) ^ (row & 7)) << 3));
#pragma unroll
          for (int qt = 0; qt < 4; ++qt) s[qt] = mfma16(kf, qa[qt][kk], s[qt]);
        }
        __builtin_amdgcn_s_setprio(0);
#pragma unroll
        for (int qt = 0; qt < 4; ++qt) {
          float p0 = fast_exp2(s[qt][0]);
          float p1 = fast_exp2(s[qt][1]);
          float p2 = fast_exp2(s[qt][2]);
          float p3 = fast_exp2(s[qt][3]);
          lsum[qt] += (p0 + p1) + (p2 + p3);
          paw[qt][2 * j] = cvt_pk(p0, p1);
          paw[qt][2 * j + 1] = cvt_pk(p2, p3);
        }
      }

      // ---- O += P V for this key-half (fragment chunk kk2=ph) ----
      __builtin_amdgcn_s_setprio(1);
#pragma unroll
      for (int ct = 0; ct < 8; ++ct) {
        int c = ct * 16 + lr;
        bf16x8 vf = ld_bf8(vb + c * 64 + (((ph * 4 + lg) ^ (c & 7)) << 3));
#pragma unroll
        for (int qt = 0; qt < 4; ++qt)
          oacc[qt][ct] = mfma16(__builtin_bit_cast(bf16x8, paw[qt]), vf, oacc[qt][ct]);
      }
      __builtin_amdgcn_s_setprio(0);
    }
  }

  // ---- epilogue: reduce l across lane groups; write unnormalized partial ----
  u16* pdst = (split == 0) ? part0 : (split == 1) ? part1 : (split == 2) ? part2 : part3;
  float* ldst = lbuf + (size_t)split * (BATCH * NSP) + (size_t)b * NSP;
#pragma unroll
  for (int qt = 0; qt < 4; ++qt) {
    lsum[qt] += __shfl_xor(lsum[qt], 16);
    lsum[qt] += __shfl_xor(lsum[qt], 32);
    if (lg == 0) ldst[i_base + qt * 16 + lr] = lsum[qt];
#pragma unroll
    for (int r = 0; r < 4; ++r) {
      int i = i_base + qt * 16 + lg * 4 + r;
      u16* row = pdst + ((size_t)b * NSP + i) * CH;
#pragma unroll
      for (int ct = 0; ct < 8; ++ct) row[ct * 16 + lr] = f2bf(oacc[qt][ct][r]);
    }
  }
}

// ---------------- combine four KV-split partials (serializes d_out scratch use) ------
__global__ __launch_bounds__(256) void combine_kernel(const u16* __restrict__ p0,
                                                      const u16* __restrict__ p1,
                                                      const u16* __restrict__ p2,
                                                      const u16* __restrict__ p3,
                                                      const float* __restrict__ lbuf,
                                                      u16* __restrict__ omid) {
  int idx = blockIdx.x * 256 + threadIdx.x;  // 0..524287
  int row = idx >> 4, coff = (idx & 15) * 8;
  const int BN = BATCH * NSP;
  float l = lbuf[row] + lbuf[BN + row] + lbuf[2 * BN + row] + lbuf[3 * BN + row];
  float inv = 1.f / l;
  bf16x8 a = ld_bf8(p0 + (size_t)row * CH + coff);
  bf16x8 bb = ld_bf8(p1 + (size_t)row * CH + coff);
  bf16x8 cc = ld_bf8(p2 + (size_t)row * CH + coff);
  bf16x8 dd = ld_bf8(p3 + (size_t)row * CH + coff);
  u16 outv[8];
#pragma unroll
  for (int e = 0; e < 8; ++e)
    outv[e] = f2bf(((float)a[e] + (float)bb[e] + (float)cc[e] + (float)dd[e]) * inv);
  *(u32x4*)(omid + (size_t)row * CH + coff) = *(const u32x4*)outv;
}

// ---------------- output projection + residual ----------------
__global__ __launch_bounds__(256) void proj_kernel(const u16* __restrict__ omid,
                                                   const u16* __restrict__ wob,
                                                   const float* __restrict__ bo,
                                                   const float* __restrict__ gamma,
                                                   const float* __restrict__ x,
                                                   float* __restrict__ out) {
  int b = blockIdx.y;
  int wave = threadIdx.x >> 6, lane = threadIdx.x & 63;
  int lr = lane & 15, lg = lane >> 4;
  int n_base = blockIdx.x * 64 + wave * 16;
  const u16* orow = omid + ((size_t)b * NSP + n_base + lr) * CH;
  f32x4 acc[8] = {};
#pragma unroll
  for (int kk = 0; kk < 4; ++kk) {
    int coff = kk * 32 + lg * 8;
    bf16x8 ofrag = ld_bf8(orow + coff);
#pragma unroll
    for (int ot = 0; ot < 8; ++ot) {
      bf16x8 wf = ld_bf8(wob + (ot * 16 + lr) * CH + coff);
      acc[ot] = mfma16(wf, ofrag, acc[ot]);
    }
  }
  float g = gamma[0];
  int n_col = n_base + lr;
#pragma unroll
  for (int ot = 0; ot < 8; ++ot) {
#pragma unroll
    for (int r = 0; r < 4; ++r) {
      int o_row = ot * 16 + lg * 4 + r;
      size_t off = ((size_t)b * CH + o_row) * NSP + n_col;
      out[off] = x[off] + g * (acc[ot][r] + bo[o_row]);
    }
  }
}

extern "C" void kernel_launch(void* const* d_in, const int* in_sizes, int n_in,
                              void* d_out, int out_size, void* d_ws, size_t ws_size,
                              hipStream_t stream) {
  const float* x = (const float*)d_in[0];
  const float* gnw = (const float*)d_in[1];
  const float* gnb = (const float*)d_in[2];
  const float* wq = (const float*)d_in[3];
  const float* bq = (const float*)d_in[4];
  const float* wk = (const float*)d_in[5];
  const float* bk = (const float*)d_in[6];
  const float* wv = (const float*)d_in[7];
  const float* bv = (const float*)d_in[8];
  const float* wo = (const float*)d_in[9];
  const float* bo = (const float*)d_in[10];
  const float* gamma = (const float*)d_in[11];
  float* out = (float*)d_out;

  const size_t BUF = (size_t)BATCH * NSP * CH * sizeof(u16);  // 8 MB
  char* ws = (char*)d_ws;
  u16* wbf = (u16*)ws;             // 4 x 128x128 bf16 = 128KB
  float* stats = (float*)(ws + 131072);
  u16* xd = (u16*)(ws + 262144);   // x_dash (b,n,c); later: split0 partial O
  u16* qb = (u16*)(ws + 262144 + BUF);
  u16* kb = (u16*)(ws + 262144 + 2 * BUF);  // later: combined O_mid
  u16* vb = (u16*)(ws + 262144 + 3 * BUF);
  float* lbuf = (float*)(ws + 262144 + 4 * BUF);  // 4 x 32768 f32 = 512KB
  const size_t need = 262144 + 4 * BUF + 524288;
  if (ws_size < need) return;
  // part1: prefer extra ws space; else reuse qb (Q read only in attn prologue; grid=512
  // at 2 blocks/CU is fully co-resident, epilogue writes land long after all Q reads)
  u16* part1 = (ws_size >= need + BUF) ? (u16*)(ws + need) : qb;
  // part2/part3 live in d_out (16 MB f32 output == exactly 2 x 8MB bf16 partials);
  // combine_kernel consumes them BEFORE proj_kernel writes d_out (stream-serialized).
  u16* part2 = (u16*)d_out;
  u16* part3 = (u16*)d_out + (size_t)BATCH * NSP * CH;

  gn_stats_kernel<<<256, 256, 0, stream>>>(x, stats, wq, wk, wv, wo, wbf);
  gn_apply_kernel<<<dim3(128, 8), 256, 0, stream>>>(x, stats, gnw, gnb, xd);
  qkv_kernel<<<dim3(64, 8), 256, 0, stream>>>(xd, wbf, wbf + 16384, wbf + 32768,
                                              bq, bk, bv, qb, kb, vb);
  attn_kernel<<<512, 256, 0, stream>>>(qb, kb, vb, xd, part1, part2, part3, lbuf);
  combine_kernel<<<2048, 256, 0, stream>>>(xd, part1, part2, part3, lbuf, kb);
  proj_kernel<<<dim3(64, 8), 256, 0, stream>>>(kb, wbf + 49152, bo, gamma, x, out);
}

// Round 12
// 170.832 us; speedup vs baseline: 1.4504x; 1.4504x over previous
//
#include <hip/hip_runtime.h>

typedef unsigned short u16;
typedef unsigned int u32;
typedef __bf16 bf16_t;
typedef bf16_t bf16x8 __attribute__((ext_vector_type(8)));
typedef float f32x4 __attribute__((ext_vector_type(4)));
typedef u32 u32x4 __attribute__((ext_vector_type(4)));

#define BATCH 8
#define CH 128
#define NSP 4096  // 64*64 spatial
#define LOG2E 1.44269504088896f

static __device__ __forceinline__ u16 f2bf(float f) {
  u32 u = __builtin_bit_cast(u32, f);
  u32 r = u + 0x7FFFu + ((u >> 16) & 1u);  // RNE
  return (u16)(r >> 16);
}

static __device__ __forceinline__ bf16x8 ld_bf8(const u16* p) {
  return __builtin_bit_cast(bf16x8, *(const u32x4*)p);
}

static __device__ __forceinline__ f32x4 mfma16(bf16x8 a, bf16x8 b, f32x4 c) {
  return __builtin_amdgcn_mfma_f32_16x16x32_bf16(a, b, c, 0, 0, 0);
}

static __device__ __forceinline__ u32 cvt_pk(float lo, float hi) {
  u32 r;
  asm("v_cvt_pk_bf16_f32 %0, %1, %2" : "=v"(r) : "v"(lo), "v"(hi));
  return r;
}

static __device__ __forceinline__ float fast_exp2(float x) {
#if __has_builtin(__builtin_amdgcn_exp2f)
  return __builtin_amdgcn_exp2f(x);
#else
  return exp2f(x);
#endif
}

static __device__ __forceinline__ void gl2lds16(const u16* g, u16* l) {
  __builtin_amdgcn_global_load_lds((const __attribute__((address_space(1))) void*)g,
                                   (__attribute__((address_space(3))) void*)l, 16, 0, 0);
}

// ---------------- GroupNorm stats (+ fused weight fp32->bf16 convert) ----------------
__global__ __launch_bounds__(256) void gn_stats_kernel(const float* __restrict__ x,
                                                       float* __restrict__ stats,
                                                       const float* __restrict__ wq,
                                                       const float* __restrict__ wk,
                                                       const float* __restrict__ wv,
                                                       const float* __restrict__ wo,
                                                       u16* __restrict__ wbf) {
  int bg = blockIdx.x;  // 0..255
  {
    int widx = bg * 256 + threadIdx.x;
    int m = widx >> 14, r = widx & 16383;
    const float* s = (m == 0) ? wq : (m == 1) ? wk : (m == 2) ? wv : wo;
    wbf[widx] = f2bf(s[r]);
  }
  const float4* p = (const float4*)(x + (size_t)bg * 16384);
  float s = 0.f, ss = 0.f;
  for (int i = threadIdx.x; i < 4096; i += 256) {
    float4 v = p[i];
    s += v.x + v.y + v.z + v.w;
    ss += v.x * v.x + v.y * v.y + v.z * v.z + v.w * v.w;
  }
  for (int off = 32; off; off >>= 1) {
    s += __shfl_xor(s, off);
    ss += __shfl_xor(ss, off);
  }
  __shared__ float rs[4], rss[4];
  int wave = threadIdx.x >> 6;
  if ((threadIdx.x & 63) == 0) { rs[wave] = s; rss[wave] = ss; }
  __syncthreads();
  if (threadIdx.x == 0) {
    s = rs[0] + rs[1] + rs[2] + rs[3];
    ss = rss[0] + rss[1] + rss[2] + rss[3];
    float mean = s * (1.f / 16384.f);
    float var = ss * (1.f / 16384.f) - mean * mean;
    stats[2 * bg] = mean;
    stats[2 * bg + 1] = rsqrtf(var + 1e-5f);
  }
}

// ---------------- GN apply + transpose (b,c,n) -> xd (b,n,c) bf16 ----------------
__global__ __launch_bounds__(256) void gn_apply_kernel(const float* __restrict__ x,
                                                       const float* __restrict__ stats,
                                                       const float* __restrict__ gnw,
                                                       const float* __restrict__ gnb,
                                                       u16* __restrict__ xd) {
  __shared__ float tile[32][129];
  __shared__ float sc[128], sh[128];
  int b = blockIdx.y, n0 = blockIdx.x * 32;
  int t = threadIdx.x;
  if (t < 128) {
    float mean = stats[2 * (b * 32 + (t >> 2))];
    float rstd = stats[2 * (b * 32 + (t >> 2)) + 1];
    float w = gnw[t];
    sc[t] = rstd * w;
    sh[t] = gnb[t] - mean * rstd * w;
  }
  const float* xb = x + (size_t)b * (CH * NSP);
#pragma unroll
  for (int r = 0; r < 16; ++r) {
    int e = t + r * 256;
    int c = e >> 5, j = e & 31;
    tile[j][c] = xb[(size_t)c * NSP + n0 + j];
  }
  __syncthreads();
  u16* xdb = xd + ((size_t)b * NSP + n0) * CH;
#pragma unroll
  for (int r = 0; r < 16; ++r) {
    int e = t + r * 256;
    int j = e >> 7, c = e & 127;
    xdb[(size_t)j * CH + c] = f2bf(tile[j][c] * sc[c] + sh[c]);
  }
}

// ---------------- fused QKV projections ----------------
// q: (b,n,c) bf16, pre-scaled by log2(e)/sqrt(C).
// k: (b,n,c') bf16 with SLOT PERMUTATION c' = ((c>>3) ^ (n&7))*8 + (c&7):
//    linear gl2lds staging then reading fragment (kk,lg) at slot (kk*4+lg)^(n&7)
//    is both correct and LDS-bank-conflict-free.
// v: (b,c,j') bf16 in PV-FRAGMENT order: within each 64-key tile, fragment
//    fr = kk2*4+lg (elements e -> keys kk2*32 + lg*4 + (e<4 ? e : 12+e)) is
//    stored at slot s = fr ^ (c&7). Inverse for key jj:
//    kk2 = jj>>5, lg = (jj&15)>>2, e = (jj&3) + (jj&16 ? 4 : 0).
__global__ __launch_bounds__(256) void qkv_kernel(const u16* __restrict__ xd,
                                                  const u16* __restrict__ wqb,
                                                  const u16* __restrict__ wkb,
                                                  const u16* __restrict__ wvb,
                                                  const float* __restrict__ bq,
                                                  const float* __restrict__ bk,
                                                  const float* __restrict__ bv,
                                                  u16* __restrict__ q, u16* __restrict__ k,
                                                  u16* __restrict__ v) {
  int b = blockIdx.y;
  int wave = threadIdx.x >> 6, lane = threadIdx.x & 63;
  int lr = lane & 15, lg = lane >> 4;
  int n_base = blockIdx.x * 64 + wave * 16;
  const u16* xrow = xd + ((size_t)b * NSP + n_base + lr) * CH;
  f32x4 accq[8] = {}, acck[8] = {}, accv[8] = {};
#pragma unroll
  for (int kk = 0; kk < 4; ++kk) {
    int coff = kk * 32 + lg * 8;
    bf16x8 xa = ld_bf8(xrow + coff);
#pragma unroll
    for (int ot = 0; ot < 8; ++ot) {
      int woff = (ot * 16 + lr) * CH + coff;
      bf16x8 wqf = ld_bf8(wqb + woff);
      bf16x8 wkf = ld_bf8(wkb + woff);
      bf16x8 wvf = ld_bf8(wvb + woff);
      accq[ot] = mfma16(xa, wqf, accq[ot]);
      acck[ot] = mfma16(xa, wkf, acck[ot]);
      accv[ot] = mfma16(wvf, xa, accv[ot]);
    }
  }
  const float qscale = 0.08838834764831845f * LOG2E;  // log2e/sqrt(128)
  // v-store fragment coords for this lane: key jj = wave*16 + lr within the tile
  int jj = wave * 16 + lr;
  int frv = (jj >> 5) * 4 + ((jj & 15) >> 2);  // kk2*4 + lg_v
  int ev = (lr & 3) + ((wave & 1) << 2);       // element within fragment
#pragma unroll
  for (int ot = 0; ot < 8; ++ot) {
    int o_col = ot * 16 + lr;
    float bqv = bq[o_col], bkv = bk[o_col];
#pragma unroll
    for (int r = 0; r < 4; ++r) {
      int nrow = n_base + lg * 4 + r;
      q[((size_t)b * NSP + nrow) * CH + o_col] = f2bf((accq[ot][r] + bqv) * qscale);
      int cperm = ((((o_col >> 3) ^ (nrow & 7)) << 3)) | (o_col & 7);
      k[((size_t)b * NSP + nrow) * CH + cperm] = f2bf(acck[ot][r] + bkv);
    }
#pragma unroll
    for (int r = 0; r < 4; ++r) {
      int c = ot * 16 + lg * 4 + r;  // v output channel
      int slot = frv ^ (c & 7);
      v[((size_t)(b * CH + c)) * NSP + blockIdx.x * 64 + slot * 8 + ev] =
          f2bf(accv[ot][r] + bv[c]);
    }
  }
}

// ---------------- flash attention (no-max, qt=4: 64 q-rows/wave, KV-split=2) --------
// 4 waves x 64 q-rows = 256 q-rows/block; KV tile 64; 32 iters/block; grid 256
// == CU count, 1 block/CU (b = id&7 -> XCD-local K/V). K,V double-buffered via
// LINEAR global_load_lds (global layouts pre-permuted so ds_reads are conflict-
// free). One barrier/iter; t+1 stages issue right after the barrier, waited a
// full iteration later by vmcnt(0).
// REGISTER FIX for r8/r9 spills (205-336MB scratch traffic): keep intrinsic
// MFMAs (compiler-managed hazards — r10/r11 hand-asm NaN'd) and lift the cap
// instead: __launch_bounds__(256, 1) -> 1 wave/SIMD -> 512-reg unified budget.
// qt=4 demand (~250: oacc 128 + qa 64 + s/paw/staging) fits with zero spills.
__global__ __launch_bounds__(256, 1) void attn_kernel(const u16* __restrict__ q,
                                                      const u16* __restrict__ k,
                                                      const u16* __restrict__ v,
                                                      u16* __restrict__ part0,
                                                      u16* __restrict__ part1,
                                                      float* __restrict__ lbuf) {
  __shared__ __align__(16) u16 kbuf[2][64 * 128];
  __shared__ __align__(16) u16 vbuf[2][128 * 64];
  int id = blockIdx.x;
  int b = id & 7;
  int qblk = (id >> 3) & 15;
  int split = (id >> 7) & 1;  // 0..1
  int wave = threadIdx.x >> 6, lane = threadIdx.x & 63;
  int lr = lane & 15, lg = lane >> 4;
  int i_base = qblk * 256 + wave * 64;
  int t0 = split * 32, t1 = t0 + 32;

  const u16* kg = k + (size_t)b * NSP * CH;
  const u16* vg = v + (size_t)b * CH * NSP;

  // staging (linear): K = 4 x 1024B (4 rows of 256B each); V = 4 x 1024B (8 rows of 128B)
  auto STAGEK = [&](int t, int bi) {
    const u16* src = kg + ((size_t)(t * 64 + wave * 16)) * CH + lane * 8;
    u16* dst = &kbuf[bi][wave * 16 * 128];
#pragma unroll
    for (int g = 0; g < 4; ++g) gl2lds16(src + g * 512, dst + g * 512);
  };
  int vco = wave * 32 + (lane >> 3);
  auto STAGEV = [&](int t, int bi) {
    const u16* src = vg + t * 64 + (lane & 7) * 8;
    u16* dst = &vbuf[bi][wave * 32 * 64];
#pragma unroll
    for (int g = 0; g < 4; ++g) gl2lds16(src + (size_t)(vco + g * 8) * NSP, dst + g * 512);
  };

  STAGEK(t0, 0);
  STAGEV(t0, 0);

  // Q fragments resident: 4 q-tiles x 4 c-chunks (B-operand: q-row at lane&15)
  bf16x8 qa[4][4];
#pragma unroll
  for (int qt = 0; qt < 4; ++qt) {
    const u16* qrow = q + ((size_t)b * NSP + i_base + qt * 16 + lr) * CH;
#pragma unroll
    for (int kk = 0; kk < 4; ++kk) qa[qt][kk] = ld_bf8(qrow + kk * 32 + lg * 8);
  }

  f32x4 oacc[4][8] = {};
  float lsum[4] = {0.f, 0.f, 0.f, 0.f};

  for (int t = t0; t < t1; ++t) {
    int bi = t & 1;
    const u16* kb = kbuf[bi];
    const u16* vb = vbuf[bi];
    asm volatile("s_waitcnt vmcnt(0)" ::: "memory");  // stages for t (issued iter t-1)
    __builtin_amdgcn_s_barrier();
    __builtin_amdgcn_sched_barrier(0);
    if (t + 1 < t1) {  // prefetch t+1 into the opposite buffers (full iter to land)
      STAGEK(t + 1, bi ^ 1);
      STAGEV(t + 1, bi ^ 1);
    }
    __builtin_amdgcn_sched_barrier(0);

    // two phases: ph=0 -> keys 0..31; ph=1 -> keys 32..63
#pragma unroll
    for (int ph = 0; ph < 2; ++ph) {
      u32x4 paw[4];
      // two 16-key sub-steps: j=0 -> paw[.][0..1], j=1 -> paw[.][2..3]
#pragma unroll
      for (int j = 0; j < 2; ++j) {
        f32x4 s[4] = {};
        int row = (ph * 2 + j) * 16 + lr;
        __builtin_amdgcn_s_setprio(1);
#pragma unroll
        for (int kk = 0; kk < 4; ++kk) {
          bf16x8 kf = ld_bf8(kb + row * 128 + (((kk * 4 + lg) ^ (row & 7)) << 3));
#pragma unroll
          for (int qt = 0; qt < 4; ++qt) s[qt] = mfma16(kf, qa[qt][kk], s[qt]);
        }
        __builtin_amdgcn_s_setprio(0);
#pragma unroll
        for (int qt = 0; qt < 4; ++qt) {
          float p0 = fast_exp2(s[qt][0]);
          float p1 = fast_exp2(s[qt][1]);
          float p2 = fast_exp2(s[qt][2]);
          float p3 = fast_exp2(s[qt][3]);
          lsum[qt] += (p0 + p1) + (p2 + p3);
          paw[qt][2 * j] = cvt_pk(p0, p1);
          paw[qt][2 * j + 1] = cvt_pk(p2, p3);
        }
      }

      // ---- O += P V for this key-half (fragment chunk kk2=ph) ----
      __builtin_amdgcn_s_setprio(1);
#pragma unroll
      for (int ct = 0; ct < 8; ++ct) {
        int c = ct * 16 + lr;
        bf16x8 vf = ld_bf8(vb + c * 64 + (((ph * 4 + lg) ^ (c & 7)) << 3));
#pragma unroll
        for (int qt = 0; qt < 4; ++qt)
          oacc[qt][ct] = mfma16(__builtin_bit_cast(bf16x8, paw[qt]), vf, oacc[qt][ct]);
      }
      __builtin_amdgcn_s_setprio(0);
    }
  }

  // ---- epilogue: reduce l across lane groups; write unnormalized partial ----
  u16* pdst = (split == 0) ? part0 : part1;
  float* ldst = lbuf + (size_t)split * (BATCH * NSP) + (size_t)b * NSP;
#pragma unroll
  for (int qt = 0; qt < 4; ++qt) {
    lsum[qt] += __shfl_xor(lsum[qt], 16);
    lsum[qt] += __shfl_xor(lsum[qt], 32);
    if (lg == 0) ldst[i_base + qt * 16 + lr] = lsum[qt];
#pragma unroll
    for (int r = 0; r < 4; ++r) {
      int i = i_base + qt * 16 + lg * 4 + r;
      u16* row = pdst + ((size_t)b * NSP + i) * CH;
#pragma unroll
      for (int ct = 0; ct < 8; ++ct) row[ct * 16 + lr] = f2bf(oacc[qt][ct][r]);
    }
  }
}

// ---------------- combine two KV-split partials (serializes d_out scratch use) ------
__global__ __launch_bounds__(256) void combine_kernel(const u16* __restrict__ p0,
                                                      const u16* __restrict__ p1,
                                                      const float* __restrict__ lbuf,
                                                      u16* __restrict__ omid) {
  int idx = blockIdx.x * 256 + threadIdx.x;  // 0..524287
  int row = idx >> 4, coff = (idx & 15) * 8;
  const int BN = BATCH * NSP;
  float l = lbuf[row] + lbuf[BN + row];
  float inv = 1.f / l;
  bf16x8 a = ld_bf8(p0 + (size_t)row * CH + coff);
  bf16x8 bb = ld_bf8(p1 + (size_t)row * CH + coff);
  u16 outv[8];
#pragma unroll
  for (int e = 0; e < 8; ++e)
    outv[e] = f2bf(((float)a[e] + (float)bb[e]) * inv);
  *(u32x4*)(omid + (size_t)row * CH + coff) = *(const u32x4*)outv;
}

// ---------------- output projection + residual ----------------
__global__ __launch_bounds__(256) void proj_kernel(const u16* __restrict__ omid,
                                                   const u16* __restrict__ wob,
                                                   const float* __restrict__ bo,
                                                   const float* __restrict__ gamma,
                                                   const float* __restrict__ x,
                                                   float* __restrict__ out) {
  int b = blockIdx.y;
  int wave = threadIdx.x >> 6, lane = threadIdx.x & 63;
  int lr = lane & 15, lg = lane >> 4;
  int n_base = blockIdx.x * 64 + wave * 16;
  const u16* orow = omid + ((size_t)b * NSP + n_base + lr) * CH;
  f32x4 acc[8] = {};
#pragma unroll
  for (int kk = 0; kk < 4; ++kk) {
    int coff = kk * 32 + lg * 8;
    bf16x8 ofrag = ld_bf8(orow + coff);
#pragma unroll
    for (int ot = 0; ot < 8; ++ot) {
      bf16x8 wf = ld_bf8(wob + (ot * 16 + lr) * CH + coff);
      acc[ot] = mfma16(wf, ofrag, acc[ot]);
    }
  }
  float g = gamma[0];
  int n_col = n_base + lr;
#pragma unroll
  for (int ot = 0; ot < 8; ++ot) {
#pragma unroll
    for (int r = 0; r < 4; ++r) {
      int o_row = ot * 16 + lg * 4 + r;
      size_t off = ((size_t)b * CH + o_row) * NSP + n_col;
      out[off] = x[off] + g * (acc[ot][r] + bo[o_row]);
    }
  }
}

extern "C" void kernel_launch(void* const* d_in, const int* in_sizes, int n_in,
                              void* d_out, int out_size, void* d_ws, size_t ws_size,
                              hipStream_t stream) {
  const float* x = (const float*)d_in[0];
  const float* gnw = (const float*)d_in[1];
  const float* gnb = (const float*)d_in[2];
  const float* wq = (const float*)d_in[3];
  const float* bq = (const float*)d_in[4];
  const float* wk = (const float*)d_in[5];
  const float* bk = (const float*)d_in[6];
  const float* wv = (const float*)d_in[7];
  const float* bv = (const float*)d_in[8];
  const float* wo = (const float*)d_in[9];
  const float* bo = (const float*)d_in[10];
  const float* gamma = (const float*)d_in[11];
  float* out = (float*)d_out;

  const size_t BUF = (size_t)BATCH * NSP * CH * sizeof(u16);  // 8 MB
  char* ws = (char*)d_ws;
  u16* wbf = (u16*)ws;             // 4 x 128x128 bf16 = 128KB
  float* stats = (float*)(ws + 131072);
  u16* xd = (u16*)(ws + 262144);   // x_dash (b,n,c); later: split0 partial O
  u16* qb = (u16*)(ws + 262144 + BUF);
  u16* kb = (u16*)(ws + 262144 + 2 * BUF);  // later: combined O_mid
  u16* vb = (u16*)(ws + 262144 + 3 * BUF);
  float* lbuf = (float*)(ws + 262144 + 4 * BUF);  // 2 x 32768 f32 = 256KB
  const size_t need = 262144 + 4 * BUF + 262144;
  if (ws_size < need) return;
  // part1 lives in d_out (16 MB f32 output holds one 8 MB bf16 partial);
  // combine_kernel consumes it BEFORE proj_kernel writes d_out (stream-serialized).
  u16* part1 = (u16*)d_out;

  gn_stats_kernel<<<256, 256, 0, stream>>>(x, stats, wq, wk, wv, wo, wbf);
  gn_apply_kernel<<<dim3(128, 8), 256, 0, stream>>>(x, stats, gnw, gnb, xd);
  qkv_kernel<<<dim3(64, 8), 256, 0, stream>>>(xd, wbf, wbf + 16384, wbf + 32768,
                                              bq, bk, bv, qb, kb, vb);
  attn_kernel<<<256, 256, 0, stream>>>(qb, kb, vb, xd, part1, lbuf);
  combine_kernel<<<2048, 256, 0, stream>>>(xd, part1, lbuf, kb);
  proj_kernel<<<dim3(64, 8), 256, 0, stream>>>(kb, wbf + 49152, bo, gamma, x, out);
}